// Round 10
// baseline (189.250 us; speedup 1.0000x reference)
//
#include <hip/hip_runtime.h>
#include <hip/hip_bf16.h>
#include <stdint.h>

typedef int i32x4 __attribute__((ext_vector_type(4)));
typedef int i32x16 __attribute__((ext_vector_type(16)));

// ---------------------------------------------------------------------------
// Pass 1: binarize f32 -> i8 sign (+1 / -1 / 0), both tensors in ONE dispatch
// (HBM-bound, ~45 us; unchanged)
// ---------------------------------------------------------------------------
__device__ __forceinline__ signed char sign_i8(float x) {
  return x > 0.0f ? (signed char)1 : (x < 0.0f ? (signed char)-1 : (signed char)0);
}

__global__ void binarize_i8_all(const float* __restrict__ x,
                                const float* __restrict__ w,
                                signed char* __restrict__ xb,
                                signed char* __restrict__ wb,
                                int n8x, int n8t) {
  int idx = blockIdx.x * blockDim.x + threadIdx.x;
  int stride = gridDim.x * blockDim.x;
  for (int i = idx; i < n8t; i += stride) {
    const float4* in4;
    uint2* out2;
    int j;
    if (i < n8x) { in4 = (const float4*)x; out2 = (uint2*)xb; j = i; }
    else         { in4 = (const float4*)w; out2 = (uint2*)wb; j = i - n8x; }
    float4 a = in4[2 * j];
    float4 b = in4[2 * j + 1];
    union { signed char c[8]; uint2 u; } p;
    p.c[0] = sign_i8(a.x); p.c[1] = sign_i8(a.y);
    p.c[2] = sign_i8(a.z); p.c[3] = sign_i8(a.w);
    p.c[4] = sign_i8(b.x); p.c[5] = sign_i8(b.y);
    p.c[6] = sign_i8(b.z); p.c[7] = sign_i8(b.w);
    out2[j] = p.u;
  }
}

// ---------------------------------------------------------------------------
// Pass 2: C = A * B^T, i8 +-1 inputs, i32 acc, f32 out (exact).
// 256x256 block tile, BK=64, 8 waves (2Mx4N), wave tile 128x64 as 4x2
// fragments of mfma_i32_32x32x32_i8 (4404 TOPS ceiling). 4-buffer LDS
// rotation (128 KiB), XOR-swizzled, global_load_lds staging.
// Round 10: k-step register pipeline with BUILTIN s_barrier. The previous
// inline-asm "s_barrier" + "memory" clobber made the compiler drain
// lgkmcnt(0)/vmcnt(0) at every barrier, force-completing prefetched ds_reads
// and serializing the LDS and MFMA pipes (sum ~2400 cyc/tile instead of
// max ~1300). Now: fragments are double-buffered at K=32 granularity; the
// next set's 6 ds_read_b128 issue un-waited, then 8 MFMAs run on the current
// set while those reads retire (compiler inserts fine-grained in-order
// lgkmcnt). __builtin_amdgcn_s_barrier() does NOT drain counters; staging
// readiness is enforced by explicit counted waitvm<4>.
// Buffer safety: all reads of buffer b are lgkm-complete before the MFMAs
// that consume them, which precede two builtin barriers before b's restage.
// __launch_bounds__(512,2): 256-reg/wave budget; acc(128 AGPR) + frags(48)
// + addressing fits. Do NOT request 4 waves/EU (round-7: acc spill, 3.3 GB
// scratch traffic).
// ---------------------------------------------------------------------------
__device__ __forceinline__ void load_lds16(const void* g, void* l) {
  __builtin_amdgcn_global_load_lds(
      (const __attribute__((address_space(1))) void*)g,
      (__attribute__((address_space(3))) void*)l,
      16, 0, 0);
}

template <int N>
__device__ __forceinline__ void waitvm() {
  asm volatile("s_waitcnt vmcnt(%0)" ::"i"(N) : "memory");
}

__global__ __launch_bounds__(512, 2)
void gemm_bt_i8(const signed char* __restrict__ A,
                const signed char* __restrict__ B,
                float* __restrict__ C,
                int M, int N, int K, int nbn) {
  constexpr int BM = 256, BN = 256, BK = 64;
  __shared__ __attribute__((aligned(16))) char lds[4 * 32768];

  // XCD-aware bijective swizzle (grid = 32*16 = 512, multiple of 8)
  int nwg = gridDim.x;
  int bid = blockIdx.x;
  int cpx = nwg >> 3;
  int swz = (bid & 7) * cpx + (bid >> 3);
  int tm = swz / nbn;
  int tn = swz % nbn;

  const int t = threadIdx.x;
  const int lane = t & 63;
  const int wid = t >> 6;       // 0..7
  const int wm = wid >> 2;      // 0..1  (wave row: 128 rows)
  const int wn = wid & 3;       // 0..3  (wave col: 64 cols)
  const int l31 = lane & 31;    // row within 32x32 fragment
  const int kq = lane >> 5;     // k-quarter: 16 contiguous k-bytes

  const size_t rowA0 = (size_t)tm * BM;
  const size_t rowB0 = (size_t)tn * BN;

  i32x16 acc[4][2] = {};

  const int nt = K / BK;  // 64

  // --- staging lane constants (inverse-swizzled global source; unchanged) ---
  const int soff0 = wid * 1024 + lane * 16;
  const int srow0 = soff0 >> 6;
  const int scb0 = ((soff0 >> 4) & 3) ^ ((srow0 >> 1) & 3);
  const int soff1 = 8192 + wid * 1024 + lane * 16;
  const int srow1 = soff1 >> 6;
  const int scb1 = ((soff1 >> 4) & 3) ^ ((srow1 >> 1) & 3);

  auto stage = [&](int tt) {
    const int b = tt & 3;
    const int k0 = tt * BK;
    load_lds16(A + (rowA0 + srow0) * K + k0 + scb0 * 16,
               lds + b * 32768 + wid * 1024);
    load_lds16(A + (rowA0 + srow1) * K + k0 + scb1 * 16,
               lds + b * 32768 + 8192 + wid * 1024);
    load_lds16(B + (rowB0 + srow0) * K + k0 + scb0 * 16,
               lds + b * 32768 + 16384 + wid * 1024);
    load_lds16(B + (rowB0 + srow1) * K + k0 + scb1 * 16,
               lds + b * 32768 + 16384 + 8192 + wid * 1024);
  };

  // --- fragment read addressing (XOR swizzle; rp independent of frag idx) ---
  const int rp = (l31 >> 1) & 3;
  const int pb0 = ((0 + kq) ^ rp) << 4;  // kstep 0: logical block kq
  const int pb1 = ((2 + kq) ^ rp) << 4;  // kstep 1: logical block 2+kq
  const int aoff = (wm * 128 + l31) * 64;
  const int boff = 16384 + (wn * 64 + l31) * 64;

  auto rdA = [&](int b, int pb, i32x4* d) {
    const char* p = lds + b * 32768 + aoff + pb;
    #pragma unroll
    for (int mf = 0; mf < 4; ++mf)
      d[mf] = *(const i32x4*)(p + mf * 2048);
  };
  auto rdB = [&](int b, int pb, i32x4* d) {
    const char* p = lds + b * 32768 + boff + pb;
    #pragma unroll
    for (int nf = 0; nf < 2; ++nf)
      d[nf] = *(const i32x4*)(p + nf * 2048);
  };
  auto mma = [&](const i32x4* a, const i32x4* bb) {
    #pragma unroll
    for (int mf = 0; mf < 4; ++mf)
      #pragma unroll
      for (int nf = 0; nf < 2; ++nf)
        acc[mf][nf] = __builtin_amdgcn_mfma_i32_32x32x32_i8(
            a[mf], bb[nf], acc[mf][nf], 0, 0, 0);
  };

  // prologue: stage 0,1; sync tile 0; stage 2; preload tile0/kstep0 frags
  stage(0); stage(1);
  waitvm<4>();
  __builtin_amdgcn_s_barrier();
  stage(2);
  i32x4 aC[4], bC[2], aN[4], bN[2];
  rdA(0, pb0, aC); rdB(0, pb0, bC);

  for (int tt = 0; tt < nt; ++tt) {
    const int b = tt & 3;

    // issue kstep-1 reads (un-waited), then MFMA on kstep-0 regs
    rdA(b, pb1, aN); rdB(b, pb1, bN);
    mma(aC, bC);

    if (tt + 1 < nt) {
      if (tt + 2 < nt) waitvm<4>(); else waitvm<0>();
      __builtin_amdgcn_s_barrier();          // tile tt+1 fully in LDS
      if (tt + 3 < nt) stage(tt + 3);
      const int b1 = (tt + 1) & 3;
      rdA(b1, pb0, aC); rdB(b1, pb0, bC);    // next tile kstep-0 (un-waited)
    }
    mma(aN, bN);                             // kstep-1
  }

  // --- epilogue: 32x32 C/D layout col=lane&31, row=(r&3)+8*(r>>2)+4*kq ---
  // i32 -> f32 conversion exact (|sum| <= 4096)
  const size_t cRow0 = rowA0 + (size_t)wm * 128;
  const size_t cCol0 = rowB0 + (size_t)wn * 64;
  const int rbase = 4 * kq;
  #pragma unroll
  for (int mf = 0; mf < 4; ++mf)
    #pragma unroll
    for (int nf = 0; nf < 2; ++nf)
      #pragma unroll
      for (int r = 0; r < 16; ++r) {
        const int row = (r & 3) + 8 * (r >> 2) + rbase;
        C[(cRow0 + mf * 32 + row) * N + cCol0 + nf * 32 + l31] =
            (float)acc[mf][nf][r];
      }
}

// ---------------------------------------------------------------------------
extern "C" void kernel_launch(void* const* d_in, const int* in_sizes, int n_in,
                              void* d_out, int out_size, void* d_ws, size_t ws_size,
                              hipStream_t stream) {
  const float* x = (const float*)d_in[0];
  const float* w = (const float*)d_in[1];
  float* out = (float*)d_out;

  const int K = 4096;
  const int M = in_sizes[0] / K;   // 8192
  const int N = in_sizes[1] / K;   // 4096

  signed char* xb = (signed char*)d_ws;
  signed char* wb = xb + (size_t)M * K;

  int n8x = (M * K) / 8;
  int n8t = n8x + (N * K) / 8;
  binarize_i8_all<<<dim3(2048), dim3(256), 0, stream>>>(x, w, xb, wb, n8x, n8t);

  int nbm = M / 256;
  int nbn = N / 256;
  gemm_bt_i8<<<dim3(nbm * nbn), dim3(512), 0, stream>>>(
      xb, wb, out, M, N, K, nbn);
}